// Round 1
// baseline (1171.020 us; speedup 1.0000x reference)
//
#include <hip/hip_runtime.h>
#include <math.h>

#define D_IN  128
#define D_HID 256
#define D_OUT 256

// ---------------------------------------------------------------- CSR build
__global__ void hist_kernel(const int* __restrict__ row, int E, int* __restrict__ deg) {
    int e = blockIdx.x * blockDim.x + threadIdx.x;
    if (e < E) atomicAdd(&deg[row[e]], 1);
}

__global__ void scan_partial(const int* __restrict__ deg, int n, int* __restrict__ partial) {
    __shared__ int sm[256];
    int i = blockIdx.x * 256 + threadIdx.x;
    sm[threadIdx.x] = (i < n) ? deg[i] : 0;
    __syncthreads();
    for (int off = 128; off > 0; off >>= 1) {
        if (threadIdx.x < off) sm[threadIdx.x] += sm[threadIdx.x + off];
        __syncthreads();
    }
    if (threadIdx.x == 0) partial[blockIdx.x] = sm[0];
}

__global__ void scan_top(int* partial, int nb) {
    __shared__ int sm[256];
    int t = threadIdx.x;
    int orig = (t < nb) ? partial[t] : 0;
    sm[t] = orig;
    __syncthreads();
    for (int off = 1; off < 256; off <<= 1) {
        int v = (t >= off) ? sm[t - off] : 0;
        __syncthreads();
        sm[t] += v;
        __syncthreads();
    }
    if (t < nb) partial[t] = sm[t] - orig;   // exclusive prefix
}

__global__ void scan_final(const int* __restrict__ deg, const int* __restrict__ partial,
                           int n, int total,
                           int* __restrict__ rowptr, int* __restrict__ cursor) {
    __shared__ int sm[256];
    int t = threadIdx.x;
    int i = blockIdx.x * 256 + t;
    int v = (i < n) ? deg[i] : 0;
    sm[t] = v;
    __syncthreads();
    for (int off = 1; off < 256; off <<= 1) {
        int u = (t >= off) ? sm[t - off] : 0;
        __syncthreads();
        sm[t] += u;
        __syncthreads();
    }
    int excl = sm[t] - v + partial[blockIdx.x];
    if (i < n) { rowptr[i] = excl; cursor[i] = excl; }
    if (i == n - 1) rowptr[n] = total;
}

__global__ void fill_kernel(const int* __restrict__ row, const int* __restrict__ colsrc, int E,
                            int* __restrict__ cursor, int* __restrict__ colout) {
    int e = blockIdx.x * blockDim.x + threadIdx.x;
    if (e < E) {
        int r = row[e];
        int slot = atomicAdd(&cursor[r], 1);
        colout[slot] = colsrc[e];
    }
}

// ---------------------------------------------------------------- aggregation
// one wave per node; D=256 -> float4 per lane, D=128 -> float2 per lane
template<int D>
__global__ void agg_kernel(const float* __restrict__ x, const int* __restrict__ rowptr,
                           const int* __restrict__ colidx, float* __restrict__ nei, int n) {
    int wave = threadIdx.x >> 6;
    int lane = threadIdx.x & 63;
    int node = blockIdx.x * 4 + wave;
    if (node >= n) return;
    int s = rowptr[node], e = rowptr[node + 1];
    float inv = 1.0f / ((float)(e - s) + 1e-12f);
    if constexpr (D == 256) {
        const float4* xp = (const float4*)x;
        float ax = 0.f, ay = 0.f, az = 0.f, aw = 0.f;
        for (int j = s; j < e; ++j) {
            int c = colidx[j];
            float4 v = xp[(size_t)c * 64 + lane];
            ax += v.x; ay += v.y; az += v.z; aw += v.w;
        }
        ((float4*)nei)[(size_t)node * 64 + lane] = make_float4(ax * inv, ay * inv, az * inv, aw * inv);
    } else {
        const float2* xp = (const float2*)x;
        float ax = 0.f, ay = 0.f;
        for (int j = s; j < e; ++j) {
            int c = colidx[j];
            float2 v = xp[(size_t)c * 64 + lane];
            ax += v.x; ay += v.y;
        }
        ((float2*)nei)[(size_t)node * 64 + lane] = make_float2(ax * inv, ay * inv);
    }
}

// ---------------------------------------------------------------- fused GEMM
// out[M,256] = epilogue( A0@B0 + A1@B1 + bias0 + bias1 )
// MODE 0: out = relu(h)
// MODE 1: out = w*extra + (1-w)*relu(h),  w = sigmoid(*alpha_p)
template<int K, int MODE>
__global__ __launch_bounds__(256)
void gemm_kernel(const float* __restrict__ A0, const float* __restrict__ A1,
                 const float* __restrict__ B0, const float* __restrict__ B1,
                 const float* __restrict__ bias0, const float* __restrict__ bias1,
                 float* __restrict__ out, const float* __restrict__ extra,
                 const float* __restrict__ alpha_p, int M) {
    constexpr int BM = 128, BN = 128, BK = 32;
    __shared__ float As[BK][BM];   // stored transposed: As[k][m]
    __shared__ float Bs[BK][BN];
    const int t = threadIdx.x;
    const int tcol = t & 15, trow = t >> 4;
    const int row0 = blockIdx.x * BM;
    const int col0 = blockIdx.y * BN;

    float acc[8][8] = {};

    for (int op = 0; op < 2; ++op) {
        const float* __restrict__ A = op ? A1 : A0;
        const float* __restrict__ B = op ? B1 : B0;
        for (int k0 = 0; k0 < K; k0 += BK) {
            __syncthreads();   // protect LDS from previous iteration's readers
            // ---- stage A tile [BM x BK] -> As[k][m]
            {
                int f4 = t & 7, rb = t >> 3;    // f4: which float4 along k, rb: row base
                #pragma unroll
                for (int i = 0; i < 4; ++i) {
                    int r = rb + 32 * i;
                    int gr = row0 + r; if (gr >= M) gr = M - 1;
                    const float4 v = *(const float4*)&A[(size_t)gr * K + k0 + f4 * 4];
                    As[f4 * 4 + 0][r] = v.x;
                    As[f4 * 4 + 1][r] = v.y;
                    As[f4 * 4 + 2][r] = v.z;
                    As[f4 * 4 + 3][r] = v.w;
                }
            }
            // ---- stage B tile [BK x BN] -> Bs[k][n]
            {
                int c4 = t & 31, kb = t >> 5;
                #pragma unroll
                for (int i = 0; i < 4; ++i) {
                    int k = kb + 8 * i;
                    const float4 v = *(const float4*)&B[(size_t)(k0 + k) * 256 + col0 + c4 * 4];
                    *(float4*)&Bs[k][c4 * 4] = v;
                }
            }
            __syncthreads();
            // ---- compute
            #pragma unroll
            for (int k = 0; k < BK; ++k) {
                float a[8], b[8];
                *(float4*)&a[0] = *(const float4*)&As[k][trow * 8];
                *(float4*)&a[4] = *(const float4*)&As[k][trow * 8 + 4];
                *(float4*)&b[0] = *(const float4*)&Bs[k][tcol * 8];
                *(float4*)&b[4] = *(const float4*)&Bs[k][tcol * 8 + 4];
                #pragma unroll
                for (int i = 0; i < 8; ++i)
                    #pragma unroll
                    for (int j = 0; j < 8; ++j)
                        acc[i][j] += a[i] * b[j];
            }
        }
    }

    // ---- epilogue
    float bsum[8];
    #pragma unroll
    for (int j = 0; j < 8; ++j) {
        int c = col0 + tcol * 8 + j;
        bsum[j] = bias0[c] + bias1[c];
    }
    float wmix = 0.f;
    if (MODE == 1) wmix = 1.0f / (1.0f + expf(-alpha_p[0]));

    #pragma unroll
    for (int i = 0; i < 8; ++i) {
        int r = row0 + trow * 8 + i;
        if (r >= M) continue;
        int cbase = col0 + tcol * 8;
        float o[8];
        #pragma unroll
        for (int j = 0; j < 8; ++j) {
            float h = acc[i][j] + bsum[j];
            o[j] = h > 0.f ? h : 0.f;
        }
        if (MODE == 1) {
            #pragma unroll
            for (int j = 0; j < 8; ++j) {
                float ex = extra[(size_t)r * 256 + cbase + j];
                o[j] = wmix * ex + (1.f - wmix) * o[j];
            }
        }
        *(float4*)&out[(size_t)r * 256 + cbase]     = make_float4(o[0], o[1], o[2], o[3]);
        *(float4*)&out[(size_t)r * 256 + cbase + 4] = make_float4(o[4], o[5], o[6], o[7]);
    }
}

// ---------------------------------------------------------------- launch
extern "C" void kernel_launch(void* const* d_in, const int* in_sizes, int n_in,
                              void* d_out, int out_size, void* d_ws, size_t ws_size,
                              hipStream_t stream) {
    const float* x       = (const float*)d_in[0];
    const float* alpha_p = (const float*)d_in[1];
    const float* s0_ws = (const float*)d_in[2],  *s0_bs = (const float*)d_in[3];
    const float* s0_wn = (const float*)d_in[4],  *s0_bn = (const float*)d_in[5];
    const float* s1_ws = (const float*)d_in[6],  *s1_bs = (const float*)d_in[7];
    const float* s1_wn = (const float*)d_in[8],  *s1_bn = (const float*)d_in[9];
    const float* a0_ws = (const float*)d_in[10], *a0_bs = (const float*)d_in[11];
    const float* a0_wn = (const float*)d_in[12], *a0_bn = (const float*)d_in[13];
    const float* a1_ws = (const float*)d_in[14], *a1_bs = (const float*)d_in[15];
    const float* a1_wn = (const float*)d_in[16], *a1_bn = (const float*)d_in[17];
    const int* es = (const int*)d_in[18];   // [2,E] row-major: row then col
    const int* ea = (const int*)d_in[19];

    const int N = in_sizes[0] / D_IN;
    const int E = in_sizes[18] / 2;
    const int* es_row = es,      *es_col = es + E;
    const int* ea_row = ea,      *ea_col = ea + E;

    float* out = (float*)d_out;   // also used as scratch for hs0/ha0

    // workspace carve-up (256B aligned)
    char* wsb = (char*)d_ws;
    size_t off = 0;
    auto carve = [&](size_t bytes) -> char* {
        char* p = wsb + off;
        off += (bytes + 255) & ~(size_t)255;
        return p;
    };
    float* nei      = (float*)carve((size_t)N * 256 * 4);
    float* hbuf     = (float*)carve((size_t)N * 256 * 4);   // hs1
    int*   deg_s    = (int*)carve((size_t)N * 4);
    int*   deg_a    = (int*)carve((size_t)N * 4);
    int*   rowptr_s = (int*)carve((size_t)(N + 1) * 4);
    int*   rowptr_a = (int*)carve((size_t)(N + 1) * 4);
    int*   cur_s    = (int*)carve((size_t)N * 4);
    int*   cur_a    = (int*)carve((size_t)N * 4);
    int*   col_s    = (int*)carve((size_t)E * 4);
    int*   col_a    = (int*)carve((size_t)E * 4);
    int*   partial  = (int*)carve(1024 * 4);

    const int EB = (E + 255) / 256;           // blocks over edges
    const int NB = (N + 255) / 256;           // blocks over nodes (<=256 required)

    // ---- CSR build: spatial
    hipMemsetAsync(deg_s, 0, (size_t)N * 4, stream);
    hipMemsetAsync(deg_a, 0, (size_t)N * 4, stream);
    hist_kernel<<<EB, 256, 0, stream>>>(es_row, E, deg_s);
    hist_kernel<<<EB, 256, 0, stream>>>(ea_row, E, deg_a);

    scan_partial<<<NB, 256, 0, stream>>>(deg_s, N, partial);
    scan_top<<<1, 256, 0, stream>>>(partial, NB);
    scan_final<<<NB, 256, 0, stream>>>(deg_s, partial, N, E, rowptr_s, cur_s);
    fill_kernel<<<EB, 256, 0, stream>>>(es_row, es_col, E, cur_s, col_s);

    scan_partial<<<NB, 256, 0, stream>>>(deg_a, N, partial);
    scan_top<<<1, 256, 0, stream>>>(partial, NB);
    scan_final<<<NB, 256, 0, stream>>>(deg_a, partial, N, E, rowptr_a, cur_a);
    fill_kernel<<<EB, 256, 0, stream>>>(ea_row, ea_col, E, cur_a, col_a);

    const int AGB = (N + 3) / 4;              // agg blocks (4 waves = 4 nodes per block)
    const int GMB = (N + 127) / 128;          // gemm row-blocks
    dim3 ggrid(GMB, 2);

    // ---- spatial stream
    agg_kernel<128><<<AGB, 256, 0, stream>>>(x, rowptr_s, col_s, nei, N);
    gemm_kernel<128, 0><<<ggrid, 256, 0, stream>>>(x, nei, s0_ws, s0_wn, s0_bs, s0_bn,
                                                   out, nullptr, alpha_p, N);
    agg_kernel<256><<<AGB, 256, 0, stream>>>(out, rowptr_s, col_s, nei, N);
    gemm_kernel<256, 0><<<ggrid, 256, 0, stream>>>(out, nei, s1_ws, s1_wn, s1_bs, s1_bn,
                                                   hbuf, nullptr, alpha_p, N);

    // ---- attribute stream
    agg_kernel<128><<<AGB, 256, 0, stream>>>(x, rowptr_a, col_a, nei, N);
    gemm_kernel<128, 0><<<ggrid, 256, 0, stream>>>(x, nei, a0_ws, a0_wn, a0_bs, a0_bn,
                                                   out, nullptr, alpha_p, N);
    agg_kernel<256><<<AGB, 256, 0, stream>>>(out, rowptr_a, col_a, nei, N);
    gemm_kernel<256, 1><<<ggrid, 256, 0, stream>>>(out, nei, a1_ws, a1_wn, a1_bs, a1_bn,
                                                   out, hbuf, alpha_p, N);

    (void)n_in; (void)out_size; (void)ws_size;
}

// Round 2
// 622.728 us; speedup vs baseline: 1.8805x; 1.8805x over previous
//
#include <hip/hip_runtime.h>
#include <math.h>

#define D_IN  128
#define D_HID 256
#define D_OUT 256

typedef __attribute__((ext_vector_type(8))) short bf16x8;
typedef __attribute__((ext_vector_type(4))) float f32x4;

__device__ __forceinline__ float bf2f(unsigned short u) {
    union { unsigned int i; float f; } v; v.i = ((unsigned int)u) << 16; return v.f;
}
__device__ __forceinline__ unsigned short f2bf(float f) {
    union { float f; unsigned int i; } v; v.f = f;
    unsigned int u = v.i;
    return (unsigned short)((u + 0x7FFFu + ((u >> 16) & 1u)) >> 16);
}

#define GLOAD_LDS16(src, dst) \
    __builtin_amdgcn_global_load_lds((const __attribute__((address_space(1))) void*)(src), \
                                     (__attribute__((address_space(3))) void*)(dst), 16, 0, 0)

// ---------------------------------------------------------------- CSR build
__global__ void hist_kernel(const int* __restrict__ row, int E, int* __restrict__ deg) {
    int e = blockIdx.x * blockDim.x + threadIdx.x;
    if (e < E) atomicAdd(&deg[row[e]], 1);
}

__global__ void scan_partial(const int* __restrict__ deg, int n, int* __restrict__ partial) {
    __shared__ int sm[256];
    int i = blockIdx.x * 256 + threadIdx.x;
    sm[threadIdx.x] = (i < n) ? deg[i] : 0;
    __syncthreads();
    for (int off = 128; off > 0; off >>= 1) {
        if (threadIdx.x < off) sm[threadIdx.x] += sm[threadIdx.x + off];
        __syncthreads();
    }
    if (threadIdx.x == 0) partial[blockIdx.x] = sm[0];
}

__global__ void scan_top(int* partial, int nb) {
    __shared__ int sm[256];
    int t = threadIdx.x;
    int orig = (t < nb) ? partial[t] : 0;
    sm[t] = orig;
    __syncthreads();
    for (int off = 1; off < 256; off <<= 1) {
        int v = (t >= off) ? sm[t - off] : 0;
        __syncthreads();
        sm[t] += v;
        __syncthreads();
    }
    if (t < nb) partial[t] = sm[t] - orig;   // exclusive prefix
}

__global__ void scan_final(const int* __restrict__ deg, const int* __restrict__ partial,
                           int n, int total,
                           int* __restrict__ rowptr, int* __restrict__ cursor) {
    __shared__ int sm[256];
    int t = threadIdx.x;
    int i = blockIdx.x * 256 + t;
    int v = (i < n) ? deg[i] : 0;
    sm[t] = v;
    __syncthreads();
    for (int off = 1; off < 256; off <<= 1) {
        int u = (t >= off) ? sm[t - off] : 0;
        __syncthreads();
        sm[t] += u;
        __syncthreads();
    }
    int excl = sm[t] - v + partial[blockIdx.x];
    if (i < n) { rowptr[i] = excl; cursor[i] = excl; }
    if (i == n - 1) rowptr[n] = total;
}

__global__ void fill_kernel(const int* __restrict__ row, const int* __restrict__ colsrc, int E,
                            int* __restrict__ cursor, int* __restrict__ colout) {
    int e = blockIdx.x * blockDim.x + threadIdx.x;
    if (e < E) {
        int r = row[e];
        int slot = atomicAdd(&cursor[r], 1);
        colout[slot] = colsrc[e];
    }
}

// ---------------------------------------------------------------- conversions
// x fp32 -> bf16, vectorized x4
__global__ void conv_x_kernel(const float* __restrict__ in, unsigned short* __restrict__ out, int n4) {
    int i = blockIdx.x * 256 + threadIdx.x;
    if (i < n4) {
        float4 v = ((const float4*)in)[i];
        ushort4 o;
        o.x = f2bf(v.x); o.y = f2bf(v.y); o.z = f2bf(v.z); o.w = f2bf(v.w);
        ((ushort4*)out)[i] = o;
    }
}

// weights fp32 [K][256] -> bf16 transposed [256][K]; 8 matrices, blockIdx.y selects
__global__ void conv_w_kernel(const float* w0, const float* w1, const float* w2, const float* w3,
                              const float* w4, const float* w5, const float* w6, const float* w7,
                              unsigned short* o0, unsigned short* o1, unsigned short* o2, unsigned short* o3,
                              unsigned short* o4, unsigned short* o5, unsigned short* o6, unsigned short* o7) {
    int m = blockIdx.y, c = blockIdx.x, k = threadIdx.x;
    const float* src; unsigned short* dst; int K;
    switch (m) {
        case 0: src = w0; dst = o0; K = 128; break;
        case 1: src = w1; dst = o1; K = 128; break;
        case 2: src = w2; dst = o2; K = 256; break;
        case 3: src = w3; dst = o3; K = 256; break;
        case 4: src = w4; dst = o4; K = 128; break;
        case 5: src = w5; dst = o5; K = 128; break;
        case 6: src = w6; dst = o6; K = 256; break;
        default: src = w7; dst = o7; K = 256; break;
    }
    if (k < K) dst[c * K + k] = f2bf(src[(size_t)k * 256 + c]);
}

// ---------------------------------------------------------------- aggregation (bf16)
// one wave per node; D=256 -> 4 bf16/lane, D=128 -> 2 bf16/lane
template<int D>
__global__ void agg_kernel(const unsigned short* __restrict__ x, const int* __restrict__ rowptr,
                           const int* __restrict__ colidx, unsigned short* __restrict__ nei, int n) {
    int wave = threadIdx.x >> 6;
    int lane = threadIdx.x & 63;
    int node = blockIdx.x * 4 + wave;
    if (node >= n) return;
    int s = rowptr[node], e = rowptr[node + 1];
    float inv = 1.0f / ((float)(e - s) + 1e-12f);
    if constexpr (D == 256) {
        float a0 = 0.f, a1 = 0.f, a2 = 0.f, a3 = 0.f;
        for (int j = s; j < e; ++j) {
            int c = colidx[j];
            ushort4 v = ((const ushort4*)x)[(size_t)c * 64 + lane];
            a0 += bf2f(v.x); a1 += bf2f(v.y); a2 += bf2f(v.z); a3 += bf2f(v.w);
        }
        ushort4 o;
        o.x = f2bf(a0 * inv); o.y = f2bf(a1 * inv); o.z = f2bf(a2 * inv); o.w = f2bf(a3 * inv);
        ((ushort4*)nei)[(size_t)node * 64 + lane] = o;
    } else {
        float a0 = 0.f, a1 = 0.f;
        for (int j = s; j < e; ++j) {
            int c = colidx[j];
            ushort2 v = ((const ushort2*)x)[(size_t)c * 64 + lane];
            a0 += bf2f(v.x); a1 += bf2f(v.y);
        }
        ushort2 o;
        o.x = f2bf(a0 * inv); o.y = f2bf(a1 * inv);
        ((ushort2*)nei)[(size_t)node * 64 + lane] = o;
    }
}

// ---------------------------------------------------------------- MFMA GEMM
// C[M,256] = epi( A0@W0 + A1@W1 + bias0 + bias1 ), A bf16 [M,K], W given as Wt bf16 [256][K]
// MODE 0: bf16 out = relu(h)
// MODE 1: fp32 out = w*extra_bf16 + (1-w)*relu(h), w = sigmoid(alpha)
template<int K, int MODE>
__global__ __launch_bounds__(256)
void gemm_mfma(const unsigned short* __restrict__ A0, const unsigned short* __restrict__ A1,
               const unsigned short* __restrict__ B0t, const unsigned short* __restrict__ B1t,
               const float* __restrict__ bias0, const float* __restrict__ bias1,
               void* __restrict__ outp, const unsigned short* __restrict__ extra,
               const float* __restrict__ alpha_p, int M) {
    constexpr int BK = 64;
    __shared__ unsigned short Asm[128 * BK];   // row-major [128][64], 16B chunks XOR-swizzled
    __shared__ unsigned short Bsm[128 * BK];   // Wt tile, same layout
    const int t = threadIdx.x;
    const int l = t & 63, w = t >> 6;
    const int wr = w >> 1, wc = w & 1;            // 2x2 wave grid, 64x64 per wave
    const int row0 = blockIdx.x * 128;
    const int col0 = blockIdx.y * 128;

    const int seg = l >> 3;                        // 0..7 row within 8-row segment
    const int src_chunk = (l & 7) ^ seg;           // inverse-swizzled source chunk

    f32x4 acc[4][4] = {};

    for (int op = 0; op < 2; ++op) {
        const unsigned short* __restrict__ A  = op ? A1  : A0;
        const unsigned short* __restrict__ Bt = op ? B1t : B0t;
        for (int k0 = 0; k0 < K; k0 += BK) {
            __syncthreads();   // previous compute done before overwrite
            #pragma unroll
            for (int i = 0; i < 4; ++i) {
                const int rbase = w * 32 + i * 8;      // tile row segment base
                // A tile
                int grow = row0 + rbase + seg; if (grow > M - 1) grow = M - 1;
                const unsigned short* asrc = A + (size_t)grow * K + k0 + src_chunk * 8;
                GLOAD_LDS16(asrc, &Asm[rbase * 64]);
                // Wt tile (rows of Wt = cols of C)
                const unsigned short* bsrc = Bt + (size_t)(col0 + rbase + seg) * K + k0 + src_chunk * 8;
                GLOAD_LDS16(bsrc, &Bsm[rbase * 64]);
            }
            __syncthreads();   // drains vmcnt (compiler full-drain before s_barrier)
            #pragma unroll
            for (int kk = 0; kk < 2; ++kk) {
                bf16x8 af[4], bfr[4];
                #pragma unroll
                for (int m = 0; m < 4; ++m) {
                    int r = wr * 64 + m * 16 + (l & 15);
                    int ch = (kk * 4 + (l >> 4)) ^ (r & 7);
                    af[m] = *(const bf16x8*)&Asm[r * 64 + ch * 8];
                }
                #pragma unroll
                for (int n = 0; n < 4; ++n) {
                    int r = wc * 64 + n * 16 + (l & 15);
                    int ch = (kk * 4 + (l >> 4)) ^ (r & 7);
                    bfr[n] = *(const bf16x8*)&Bsm[r * 64 + ch * 8];
                }
                #pragma unroll
                for (int m = 0; m < 4; ++m)
                    #pragma unroll
                    for (int n = 0; n < 4; ++n)
                        acc[m][n] = __builtin_amdgcn_mfma_f32_16x16x32_bf16(af[m], bfr[n], acc[m][n], 0, 0, 0);
            }
        }
    }

    // ---- epilogue: C row = row0+wr*64+m*16+(l>>4)*4+i, col = col0+wc*64+n*16+(l&15)
    float bsum[4];
    int cidx[4];
    #pragma unroll
    for (int n = 0; n < 4; ++n) {
        cidx[n] = col0 + wc * 64 + n * 16 + (l & 15);
        bsum[n] = bias0[cidx[n]] + bias1[cidx[n]];
    }
    float wmix = 0.f;
    if (MODE == 1) wmix = 1.0f / (1.0f + expf(-alpha_p[0]));

    #pragma unroll
    for (int m = 0; m < 4; ++m) {
        #pragma unroll
        for (int i = 0; i < 4; ++i) {
            int r = row0 + wr * 64 + m * 16 + (l >> 4) * 4 + i;
            if (r >= M) continue;
            #pragma unroll
            for (int n = 0; n < 4; ++n) {
                float h = acc[m][n][i] + bsum[n];
                float o = h > 0.f ? h : 0.f;
                if (MODE == 0) {
                    ((unsigned short*)outp)[(size_t)r * 256 + cidx[n]] = f2bf(o);
                } else {
                    float ex = bf2f(extra[(size_t)r * 256 + cidx[n]]);
                    ((float*)outp)[(size_t)r * 256 + cidx[n]] = wmix * ex + (1.f - wmix) * o;
                }
            }
        }
    }
}

// ---------------------------------------------------------------- launch
extern "C" void kernel_launch(void* const* d_in, const int* in_sizes, int n_in,
                              void* d_out, int out_size, void* d_ws, size_t ws_size,
                              hipStream_t stream) {
    const float* x       = (const float*)d_in[0];
    const float* alpha_p = (const float*)d_in[1];
    const float* s0_ws = (const float*)d_in[2],  *s0_bs = (const float*)d_in[3];
    const float* s0_wn = (const float*)d_in[4],  *s0_bn = (const float*)d_in[5];
    const float* s1_ws = (const float*)d_in[6],  *s1_bs = (const float*)d_in[7];
    const float* s1_wn = (const float*)d_in[8],  *s1_bn = (const float*)d_in[9];
    const float* a0_ws = (const float*)d_in[10], *a0_bs = (const float*)d_in[11];
    const float* a0_wn = (const float*)d_in[12], *a0_bn = (const float*)d_in[13];
    const float* a1_ws = (const float*)d_in[14], *a1_bs = (const float*)d_in[15];
    const float* a1_wn = (const float*)d_in[16], *a1_bn = (const float*)d_in[17];
    const int* es = (const int*)d_in[18];   // [2,E]: row then col
    const int* ea = (const int*)d_in[19];

    const int N = in_sizes[0] / D_IN;
    const int E = in_sizes[18] / 2;
    const int* es_row = es, *es_col = es + E;
    const int* ea_row = ea, *ea_col = ea + E;

    // workspace carve-up (256B aligned)
    char* wsb = (char*)d_ws;
    size_t off = 0;
    auto carve = [&](size_t bytes) -> char* {
        char* p = wsb + off;
        off += (bytes + 255) & ~(size_t)255;
        return p;
    };
    unsigned short* xb   = (unsigned short*)carve((size_t)N * 128 * 2);   // x bf16
    unsigned short* neib = (unsigned short*)carve((size_t)N * 256 * 2);   // nei bf16
    unsigned short* actb = (unsigned short*)carve((size_t)N * 256 * 2);   // hs0/ha0 bf16
    unsigned short* hb   = (unsigned short*)carve((size_t)N * 256 * 2);   // hs1 bf16
    unsigned short* wt[8];
    const int wK[8] = {128, 128, 256, 256, 128, 128, 256, 256};
    for (int i = 0; i < 8; ++i) wt[i] = (unsigned short*)carve((size_t)wK[i] * 256 * 2);
    int* deg_s    = (int*)carve((size_t)N * 4);
    int* deg_a    = (int*)carve((size_t)N * 4);
    int* rowptr_s = (int*)carve((size_t)(N + 1) * 4);
    int* rowptr_a = (int*)carve((size_t)(N + 1) * 4);
    int* cur_s    = (int*)carve((size_t)N * 4);
    int* cur_a    = (int*)carve((size_t)N * 4);
    int* col_s    = (int*)carve((size_t)E * 4);
    int* col_a    = (int*)carve((size_t)E * 4);
    int* partial  = (int*)carve(1024 * 4);

    const int EB = (E + 255) / 256;
    const int NB = (N + 255) / 256;

    // ---- conversions
    conv_x_kernel<<<(N * 128 / 4 + 255) / 256, 256, 0, stream>>>(x, xb, N * 128 / 4);
    conv_w_kernel<<<dim3(256, 8), 256, 0, stream>>>(s0_ws, s0_wn, s1_ws, s1_wn,
                                                    a0_ws, a0_wn, a1_ws, a1_wn,
                                                    wt[0], wt[1], wt[2], wt[3],
                                                    wt[4], wt[5], wt[6], wt[7]);

    // ---- CSR build
    hipMemsetAsync(deg_s, 0, (size_t)N * 4, stream);
    hipMemsetAsync(deg_a, 0, (size_t)N * 4, stream);
    hist_kernel<<<EB, 256, 0, stream>>>(es_row, E, deg_s);
    hist_kernel<<<EB, 256, 0, stream>>>(ea_row, E, deg_a);

    scan_partial<<<NB, 256, 0, stream>>>(deg_s, N, partial);
    scan_top<<<1, 256, 0, stream>>>(partial, NB);
    scan_final<<<NB, 256, 0, stream>>>(deg_s, partial, N, E, rowptr_s, cur_s);
    fill_kernel<<<EB, 256, 0, stream>>>(es_row, es_col, E, cur_s, col_s);

    scan_partial<<<NB, 256, 0, stream>>>(deg_a, N, partial);
    scan_top<<<1, 256, 0, stream>>>(partial, NB);
    scan_final<<<NB, 256, 0, stream>>>(deg_a, partial, N, E, rowptr_a, cur_a);
    fill_kernel<<<EB, 256, 0, stream>>>(ea_row, ea_col, E, cur_a, col_a);

    const int AGB = (N + 3) / 4;
    const int GMB = (N + 127) / 128;
    dim3 ggrid(GMB, 2);

    // ---- spatial stream
    agg_kernel<128><<<AGB, 256, 0, stream>>>(xb, rowptr_s, col_s, neib, N);
    gemm_mfma<128, 0><<<ggrid, 256, 0, stream>>>(xb, neib, wt[0], wt[1], s0_bs, s0_bn,
                                                 actb, nullptr, alpha_p, N);
    agg_kernel<256><<<AGB, 256, 0, stream>>>(actb, rowptr_s, col_s, neib, N);
    gemm_mfma<256, 0><<<ggrid, 256, 0, stream>>>(actb, neib, wt[2], wt[3], s1_bs, s1_bn,
                                                 hb, nullptr, alpha_p, N);

    // ---- attribute stream
    agg_kernel<128><<<AGB, 256, 0, stream>>>(xb, rowptr_a, col_a, neib, N);
    gemm_mfma<128, 0><<<ggrid, 256, 0, stream>>>(xb, neib, wt[4], wt[5], a0_bs, a0_bn,
                                                 actb, nullptr, alpha_p, N);
    agg_kernel<256><<<AGB, 256, 0, stream>>>(actb, rowptr_a, col_a, neib, N);
    gemm_mfma<256, 1><<<ggrid, 256, 0, stream>>>(actb, neib, wt[6], wt[7], a1_bs, a1_bn,
                                                 d_out, hb, alpha_p, N);

    (void)n_in; (void)out_size; (void)ws_size;
}

// Round 3
// 470.273 us; speedup vs baseline: 2.4901x; 1.3242x over previous
//
#include <hip/hip_runtime.h>
#include <math.h>

#define D_IN  128
#define D_HID 256
#define D_OUT 256

typedef __attribute__((ext_vector_type(8))) short bf16x8;
typedef __attribute__((ext_vector_type(4))) float f32x4;

__device__ __forceinline__ float bf2f(unsigned short u) {
    union { unsigned int i; float f; } v; v.i = ((unsigned int)u) << 16; return v.f;
}
__device__ __forceinline__ unsigned short f2bf(float f) {
    union { float f; unsigned int i; } v; v.f = f;
    unsigned int u = v.i;
    return (unsigned short)((u + 0x7FFFu + ((u >> 16) & 1u)) >> 16);
}

#define GLOAD_LDS16(src, dst) \
    __builtin_amdgcn_global_load_lds((const __attribute__((address_space(1))) void*)(src), \
                                     (__attribute__((address_space(3))) void*)(dst), 16, 0, 0)

// ---------------------------------------------------------------- CSR build (both edge sets, grid.y selects)
__global__ void hist2(const int* __restrict__ r0, const int* __restrict__ r1, int E,
                      int* __restrict__ d0, int* __restrict__ d1) {
    const int* r = blockIdx.y ? r1 : r0;
    int* d = blockIdx.y ? d1 : d0;
    int e = blockIdx.x * 256 + threadIdx.x;
    if (e < E) atomicAdd(&d[r[e]], 1);
}

__global__ void scan_partial2(const int* __restrict__ dg0, const int* __restrict__ dg1, int n,
                              int* __restrict__ p0, int* __restrict__ p1) {
    const int* deg = blockIdx.y ? dg1 : dg0;
    int* partial = blockIdx.y ? p1 : p0;
    __shared__ int sm[256];
    int i = blockIdx.x * 256 + threadIdx.x;
    sm[threadIdx.x] = (i < n) ? deg[i] : 0;
    __syncthreads();
    for (int off = 128; off > 0; off >>= 1) {
        if (threadIdx.x < off) sm[threadIdx.x] += sm[threadIdx.x + off];
        __syncthreads();
    }
    if (threadIdx.x == 0) partial[blockIdx.x] = sm[0];
}

__global__ void scan_top2(int* p0, int* p1, int nb) {
    int* partial = blockIdx.x ? p1 : p0;
    __shared__ int sm[256];
    int t = threadIdx.x;
    int orig = (t < nb) ? partial[t] : 0;
    sm[t] = orig;
    __syncthreads();
    for (int off = 1; off < 256; off <<= 1) {
        int v = (t >= off) ? sm[t - off] : 0;
        __syncthreads();
        sm[t] += v;
        __syncthreads();
    }
    if (t < nb) partial[t] = sm[t] - orig;   // exclusive prefix
}

__global__ void scan_final2(const int* __restrict__ dg0, const int* __restrict__ dg1,
                            const int* __restrict__ p0, const int* __restrict__ p1,
                            int n, int total,
                            int* __restrict__ rp0, int* __restrict__ rp1,
                            int* __restrict__ cu0, int* __restrict__ cu1) {
    const int* deg = blockIdx.y ? dg1 : dg0;
    const int* partial = blockIdx.y ? p1 : p0;
    int* rowptr = blockIdx.y ? rp1 : rp0;
    int* cursor = blockIdx.y ? cu1 : cu0;
    __shared__ int sm[256];
    int t = threadIdx.x;
    int i = blockIdx.x * 256 + t;
    int v = (i < n) ? deg[i] : 0;
    sm[t] = v;
    __syncthreads();
    for (int off = 1; off < 256; off <<= 1) {
        int u = (t >= off) ? sm[t - off] : 0;
        __syncthreads();
        sm[t] += u;
        __syncthreads();
    }
    int excl = sm[t] - v + partial[blockIdx.x];
    if (i < n) { rowptr[i] = excl; cursor[i] = excl; }
    if (i == n - 1) rowptr[n] = total;
}

__global__ void fill2(const int* __restrict__ r0, const int* __restrict__ c0,
                      const int* __restrict__ r1, const int* __restrict__ c1, int E,
                      int* __restrict__ cu0, int* __restrict__ cu1,
                      int* __restrict__ o0, int* __restrict__ o1) {
    const int* row = blockIdx.y ? r1 : r0;
    const int* colsrc = blockIdx.y ? c1 : c0;
    int* cursor = blockIdx.y ? cu1 : cu0;
    int* colout = blockIdx.y ? o1 : o0;
    int e = blockIdx.x * 256 + threadIdx.x;
    if (e < E) {
        int r = row[e];
        int slot = atomicAdd(&cursor[r], 1);
        colout[slot] = colsrc[e];
    }
}

// ---------------------------------------------------------------- conversions
__global__ void conv_x_kernel(const float* __restrict__ in, unsigned short* __restrict__ out, int n4) {
    int i = blockIdx.x * 256 + threadIdx.x;
    if (i < n4) {
        float4 v = ((const float4*)in)[i];
        ushort4 o;
        o.x = f2bf(v.x); o.y = f2bf(v.y); o.z = f2bf(v.z); o.w = f2bf(v.w);
        ((ushort4*)out)[i] = o;
    }
}

__global__ void conv_w_kernel(const float* w0, const float* w1, const float* w2, const float* w3,
                              const float* w4, const float* w5, const float* w6, const float* w7,
                              unsigned short* o0, unsigned short* o1, unsigned short* o2, unsigned short* o3,
                              unsigned short* o4, unsigned short* o5, unsigned short* o6, unsigned short* o7) {
    int m = blockIdx.y, c = blockIdx.x, k = threadIdx.x;
    const float* src; unsigned short* dst; int K;
    switch (m) {
        case 0: src = w0; dst = o0; K = 128; break;
        case 1: src = w1; dst = o1; K = 128; break;
        case 2: src = w2; dst = o2; K = 256; break;
        case 3: src = w3; dst = o3; K = 256; break;
        case 4: src = w4; dst = o4; K = 128; break;
        case 5: src = w5; dst = o5; K = 128; break;
        case 6: src = w6; dst = o6; K = 256; break;
        default: src = w7; dst = o7; K = 256; break;
    }
    if (k < K) dst[c * K + k] = f2bf(src[(size_t)k * 256 + c]);
}

// ---------------------------------------------------------------- aggregation (bf16, 2 streams fused)
// one wave per node; blockIdx.y selects stream; 4-way unrolled gather for ILP
template<int D>
__global__ void agg2(const unsigned short* __restrict__ x0, const unsigned short* __restrict__ x1,
                     const int* __restrict__ rp0, const int* __restrict__ ci0,
                     const int* __restrict__ rp1, const int* __restrict__ ci1,
                     unsigned short* __restrict__ n0, unsigned short* __restrict__ n1, int n) {
    const unsigned short* x = blockIdx.y ? x1 : x0;
    const int* rowptr = blockIdx.y ? rp1 : rp0;
    const int* colidx = blockIdx.y ? ci1 : ci0;
    unsigned short* nei = blockIdx.y ? n1 : n0;

    int wave = threadIdx.x >> 6;
    int lane = threadIdx.x & 63;
    int node = blockIdx.x * 4 + wave;
    if (node >= n) return;
    int s = rowptr[node], e = rowptr[node + 1];
    float inv = 1.0f / ((float)(e - s) + 1e-12f);

    if constexpr (D == 256) {
        const ushort4* xp = (const ushort4*)x;
        float p0[4] = {}, p1[4] = {}, p2[4] = {}, p3[4] = {};
        int j = s;
        for (; j + 4 <= e; j += 4) {
            int c0 = colidx[j], c1 = colidx[j + 1], c2 = colidx[j + 2], c3 = colidx[j + 3];
            ushort4 v0 = xp[(size_t)c0 * 64 + lane];
            ushort4 v1 = xp[(size_t)c1 * 64 + lane];
            ushort4 v2 = xp[(size_t)c2 * 64 + lane];
            ushort4 v3 = xp[(size_t)c3 * 64 + lane];
            p0[0] += bf2f(v0.x); p0[1] += bf2f(v0.y); p0[2] += bf2f(v0.z); p0[3] += bf2f(v0.w);
            p1[0] += bf2f(v1.x); p1[1] += bf2f(v1.y); p1[2] += bf2f(v1.z); p1[3] += bf2f(v1.w);
            p2[0] += bf2f(v2.x); p2[1] += bf2f(v2.y); p2[2] += bf2f(v2.z); p2[3] += bf2f(v2.w);
            p3[0] += bf2f(v3.x); p3[1] += bf2f(v3.y); p3[2] += bf2f(v3.z); p3[3] += bf2f(v3.w);
        }
        for (; j < e; ++j) {
            int c = colidx[j];
            ushort4 v = xp[(size_t)c * 64 + lane];
            p0[0] += bf2f(v.x); p0[1] += bf2f(v.y); p0[2] += bf2f(v.z); p0[3] += bf2f(v.w);
        }
        ushort4 o;
        o.x = f2bf((p0[0] + p1[0] + p2[0] + p3[0]) * inv);
        o.y = f2bf((p0[1] + p1[1] + p2[1] + p3[1]) * inv);
        o.z = f2bf((p0[2] + p1[2] + p2[2] + p3[2]) * inv);
        o.w = f2bf((p0[3] + p1[3] + p2[3] + p3[3]) * inv);
        ((ushort4*)nei)[(size_t)node * 64 + lane] = o;
    } else {
        const ushort2* xp = (const ushort2*)x;
        float p0[2] = {}, p1[2] = {}, p2[2] = {}, p3[2] = {};
        int j = s;
        for (; j + 4 <= e; j += 4) {
            int c0 = colidx[j], c1 = colidx[j + 1], c2 = colidx[j + 2], c3 = colidx[j + 3];
            ushort2 v0 = xp[(size_t)c0 * 64 + lane];
            ushort2 v1 = xp[(size_t)c1 * 64 + lane];
            ushort2 v2 = xp[(size_t)c2 * 64 + lane];
            ushort2 v3 = xp[(size_t)c3 * 64 + lane];
            p0[0] += bf2f(v0.x); p0[1] += bf2f(v0.y);
            p1[0] += bf2f(v1.x); p1[1] += bf2f(v1.y);
            p2[0] += bf2f(v2.x); p2[1] += bf2f(v2.y);
            p3[0] += bf2f(v3.x); p3[1] += bf2f(v3.y);
        }
        for (; j < e; ++j) {
            int c = colidx[j];
            ushort2 v = xp[(size_t)c * 64 + lane];
            p0[0] += bf2f(v.x); p0[1] += bf2f(v.y);
        }
        ushort2 o;
        o.x = f2bf((p0[0] + p1[0] + p2[0] + p3[0]) * inv);
        o.y = f2bf((p0[1] + p1[1] + p2[1] + p3[1]) * inv);
        ((ushort2*)nei)[(size_t)node * 64 + lane] = o;
    }
}

// ---------------------------------------------------------------- MFMA GEMM (2-phase dbuf pipeline)
struct GemmArgs {
    const unsigned short* A0;
    const unsigned short* A1;
    const unsigned short* B0t;
    const unsigned short* B1t;
    const float* bias0;
    const float* bias1;
    void* out;
};

// C[M,256] = epi( A0@W0 + A1@W1 + b0 + b1 ); blockIdx.z selects g0/g1
// MODE 0: bf16 out = relu(h);  MODE 1: fp32 out = w*extra + (1-w)*relu(h)
template<int K, int MODE>
__global__ __launch_bounds__(256)
void gemm_mfma(GemmArgs g0, GemmArgs g1, const unsigned short* __restrict__ extra,
               const float* __restrict__ alpha_p, int M) {
    constexpr int BK = 64;
    constexpr int NT = 2 * K / BK;                 // tiles across both operand pairs
    __shared__ unsigned short Asm[2][128 * BK];    // [128][64] row-major, 16B chunks XOR-swizzled
    __shared__ unsigned short Bsm[2][128 * BK];
    const GemmArgs g = blockIdx.z ? g1 : g0;
    const int t = threadIdx.x;
    const int l = t & 63, w = t >> 6;
    const int wr = w >> 1, wc = w & 1;             // 2x2 wave grid, 64x64 per wave
    const int row0 = blockIdx.x * 128;
    const int col0 = blockIdx.y * 128;

    const int seg = l >> 3;                        // row within 8-row segment
    const int src_chunk = (l & 7) ^ seg;           // inverse-swizzled source chunk

    f32x4 acc[4][4] = {};

    auto STAGE = [&](int tt, int buf) {
        const int op = tt >= (K / BK);
        const int k0 = (tt - op * (K / BK)) * BK;
        const unsigned short* __restrict__ A  = op ? g.A1  : g.A0;
        const unsigned short* __restrict__ Bt = op ? g.B1t : g.B0t;
        #pragma unroll
        for (int i = 0; i < 4; ++i) {
            const int rbase = w * 32 + i * 8;
            int grow = row0 + rbase + seg; if (grow > M - 1) grow = M - 1;
            GLOAD_LDS16(A + (size_t)grow * K + k0 + src_chunk * 8, &Asm[buf][rbase * 64]);
            GLOAD_LDS16(Bt + (size_t)(col0 + rbase + seg) * K + k0 + src_chunk * 8, &Bsm[buf][rbase * 64]);
        }
    };

    STAGE(0, 0);
    #pragma unroll
    for (int tt = 0; tt < NT; ++tt) {
        const int cur = tt & 1;
        if (tt + 1 < NT) {
            STAGE(tt + 1, cur ^ 1);
            asm volatile("s_waitcnt vmcnt(8)" ::: "memory");   // current buf's 8 loads done
        } else {
            asm volatile("s_waitcnt vmcnt(0)" ::: "memory");
        }
        __builtin_amdgcn_s_barrier();
        #pragma unroll
        for (int kk = 0; kk < 2; ++kk) {
            bf16x8 af[4], bfr[4];
            #pragma unroll
            for (int m = 0; m < 4; ++m) {
                int r = wr * 64 + m * 16 + (l & 15);
                int ch = (kk * 4 + (l >> 4)) ^ (r & 7);
                af[m] = *(const bf16x8*)&Asm[cur][r * 64 + ch * 8];
            }
            #pragma unroll
            for (int n = 0; n < 4; ++n) {
                int r = wc * 64 + n * 16 + (l & 15);
                int ch = (kk * 4 + (l >> 4)) ^ (r & 7);
                bfr[n] = *(const bf16x8*)&Bsm[cur][r * 64 + ch * 8];
            }
            #pragma unroll
            for (int m = 0; m < 4; ++m)
                #pragma unroll
                for (int n = 0; n < 4; ++n)
                    acc[m][n] = __builtin_amdgcn_mfma_f32_16x16x32_bf16(af[m], bfr[n], acc[m][n], 0, 0, 0);
        }
        // all LDS reads of buf[cur] drained before next STAGE overwrites it
        asm volatile("s_waitcnt lgkmcnt(0)" ::: "memory");
        __builtin_amdgcn_s_barrier();
    }

    // ---- epilogue: row = row0+wr*64+m*16+(l>>4)*4+i, col = col0+wc*64+n*16+(l&15)
    float bsum[4];
    int cidx[4];
    #pragma unroll
    for (int n = 0; n < 4; ++n) {
        cidx[n] = col0 + wc * 64 + n * 16 + (l & 15);
        bsum[n] = g.bias0[cidx[n]] + g.bias1[cidx[n]];
    }
    float wmix = 0.f;
    if (MODE == 1) wmix = 1.0f / (1.0f + expf(-alpha_p[0]));

    #pragma unroll
    for (int m = 0; m < 4; ++m) {
        #pragma unroll
        for (int i = 0; i < 4; ++i) {
            int r = row0 + wr * 64 + m * 16 + (l >> 4) * 4 + i;
            if (r >= M) continue;
            #pragma unroll
            for (int n = 0; n < 4; ++n) {
                float h = acc[m][n][i] + bsum[n];
                float o = h > 0.f ? h : 0.f;
                if (MODE == 0) {
                    ((unsigned short*)g.out)[(size_t)r * 256 + cidx[n]] = f2bf(o);
                } else {
                    float ex = bf2f(extra[(size_t)r * 256 + cidx[n]]);
                    ((float*)g.out)[(size_t)r * 256 + cidx[n]] = wmix * ex + (1.f - wmix) * o;
                }
            }
        }
    }
}

// ---------------------------------------------------------------- launch
extern "C" void kernel_launch(void* const* d_in, const int* in_sizes, int n_in,
                              void* d_out, int out_size, void* d_ws, size_t ws_size,
                              hipStream_t stream) {
    const float* x       = (const float*)d_in[0];
    const float* alpha_p = (const float*)d_in[1];
    const float* s0_ws = (const float*)d_in[2],  *s0_bs = (const float*)d_in[3];
    const float* s0_wn = (const float*)d_in[4],  *s0_bn = (const float*)d_in[5];
    const float* s1_ws = (const float*)d_in[6],  *s1_bs = (const float*)d_in[7];
    const float* s1_wn = (const float*)d_in[8],  *s1_bn = (const float*)d_in[9];
    const float* a0_ws = (const float*)d_in[10], *a0_bs = (const float*)d_in[11];
    const float* a0_wn = (const float*)d_in[12], *a0_bn = (const float*)d_in[13];
    const float* a1_ws = (const float*)d_in[14], *a1_bs = (const float*)d_in[15];
    const float* a1_wn = (const float*)d_in[16], *a1_bn = (const float*)d_in[17];
    const int* es = (const int*)d_in[18];   // [2,E]: row then col
    const int* ea = (const int*)d_in[19];

    const int N = in_sizes[0] / D_IN;
    const int E = in_sizes[18] / 2;
    const int* es_row = es, *es_col = es + E;
    const int* ea_row = ea, *ea_col = ea + E;

    // workspace carve-up (256B aligned)
    char* wsb = (char*)d_ws;
    size_t off = 0;
    auto carve = [&](size_t bytes) -> char* {
        char* p = wsb + off;
        off += (bytes + 255) & ~(size_t)255;
        return p;
    };
    unsigned short* xb     = (unsigned short*)carve((size_t)N * 128 * 2);   // x bf16
    unsigned short* neib_s = (unsigned short*)carve((size_t)N * 256 * 2);
    unsigned short* neib_a = (unsigned short*)carve((size_t)N * 256 * 2);
    unsigned short* actb_a = (unsigned short*)carve((size_t)N * 256 * 2);   // ha0
    unsigned short* hb     = (unsigned short*)carve((size_t)N * 256 * 2);   // hs1
    unsigned short* actb_s = (unsigned short*)d_out;                        // hs0 (scratch; dead before final write)
    unsigned short* wt[8];
    const int wK[8] = {128, 128, 256, 256, 128, 128, 256, 256};
    for (int i = 0; i < 8; ++i) wt[i] = (unsigned short*)carve((size_t)wK[i] * 256 * 2);
    int* deg      = (int*)carve((size_t)2 * N * 4);
    int* deg_s    = deg, *deg_a = deg + N;
    int* rowptr_s = (int*)carve((size_t)(N + 1) * 4);
    int* rowptr_a = (int*)carve((size_t)(N + 1) * 4);
    int* cur_s    = (int*)carve((size_t)N * 4);
    int* cur_a    = (int*)carve((size_t)N * 4);
    int* col_s    = (int*)carve((size_t)E * 4);
    int* col_a    = (int*)carve((size_t)E * 4);
    int* part_s   = (int*)carve(256 * 4);
    int* part_a   = (int*)carve(256 * 4);

    const int EB = (E + 255) / 256;
    const int NB = (N + 255) / 256;

    // ---- conversions
    conv_x_kernel<<<(N * 128 / 4 + 255) / 256, 256, 0, stream>>>(x, xb, N * 128 / 4);
    conv_w_kernel<<<dim3(256, 8), 256, 0, stream>>>(s0_ws, s0_wn, s1_ws, s1_wn,
                                                    a0_ws, a0_wn, a1_ws, a1_wn,
                                                    wt[0], wt[1], wt[2], wt[3],
                                                    wt[4], wt[5], wt[6], wt[7]);

    // ---- CSR build (both edge sets)
    hipMemsetAsync(deg, 0, (size_t)2 * N * 4, stream);
    hist2<<<dim3(EB, 2), 256, 0, stream>>>(es_row, ea_row, E, deg_s, deg_a);
    scan_partial2<<<dim3(NB, 2), 256, 0, stream>>>(deg_s, deg_a, N, part_s, part_a);
    scan_top2<<<2, 256, 0, stream>>>(part_s, part_a, NB);
    scan_final2<<<dim3(NB, 2), 256, 0, stream>>>(deg_s, deg_a, part_s, part_a, N, E,
                                                 rowptr_s, rowptr_a, cur_s, cur_a);
    fill2<<<dim3(EB, 2), 256, 0, stream>>>(es_row, es_col, ea_row, ea_col, E,
                                           cur_s, cur_a, col_s, col_a);

    const int AGB = (N + 3) / 4;
    const int GMB = (N + 127) / 128;

    GemmArgs l0s = { xb, neib_s, wt[0], wt[1], s0_bs, s0_bn, actb_s };
    GemmArgs l0a = { xb, neib_a, wt[4], wt[5], a0_bs, a0_bn, actb_a };
    GemmArgs l1s = { actb_s, neib_s, wt[2], wt[3], s1_bs, s1_bn, hb };
    GemmArgs l1a = { actb_a, neib_a, wt[6], wt[7], a1_bs, a1_bn, d_out };

    // ---- layer 0 (both streams fused)
    agg2<128><<<dim3(AGB, 2), 256, 0, stream>>>(xb, xb, rowptr_s, col_s, rowptr_a, col_a,
                                                neib_s, neib_a, N);
    gemm_mfma<128, 0><<<dim3(GMB, 2, 2), 256, 0, stream>>>(l0s, l0a, nullptr, alpha_p, N);

    // ---- layer 1 (agg fused; gemms ordered: attr mixes in hs1)
    agg2<256><<<dim3(AGB, 2), 256, 0, stream>>>(actb_s, actb_a, rowptr_s, col_s, rowptr_a, col_a,
                                                neib_s, neib_a, N);
    gemm_mfma<256, 0><<<dim3(GMB, 2, 1), 256, 0, stream>>>(l1s, l1s, nullptr, alpha_p, N);
    gemm_mfma<256, 1><<<dim3(GMB, 2, 1), 256, 0, stream>>>(l1a, l1a, hb, alpha_p, N);

    (void)n_in; (void)out_size; (void)ws_size;
}